// Round 8
// baseline (362.223 us; speedup 1.0000x reference)
//
#include <hip/hip_runtime.h>
#include <math.h>

// Problem shape (fixed by reference setup_inputs):
//   images [32][256][64][64] fp32, words [32][32][768] fp32, mask [32][32] bool,
//   W [256][768] fp32, b [256] fp32
//   out0 weighted_words [32][256][64][64], out1 attn_out [32][32][64][64], fp32 concat.
#define B_   32
#define NC_  256
#define HW_  4096
#define MW_  32
#define E_   768
#define NEG_BIG -3.0e38f

// Native Clang vector types: __builtin_nontemporal_* accepts these
// (HIP's float2/float4 are classes and are rejected -- R5 compile failure).
typedef float vf2 __attribute__((ext_vector_type(2)));
typedef float vf4 __attribute__((ext_vector_type(4)));

// Workspace layout (float offsets).
#define PART_OFF   0          // partial GEMM: 8 chunks * 32b * 32m * 256c = 2097152 floats
#define WT_OFF     2359296    // W transposed [e][c]: 196608 floats
#define WORDST_OFF 2555904    // words transposed [b][e][m]: 786432 floats

// ---------------------------------------------------------------------------
// Prep: tiled transposes only (W 256x768 -> WT 768x256; words[b] 32x768 ->
// wordsT[b] 768x32). Mask handling lives in attention.
// Blocks 0..191: W transpose. 192..959: words transpose.
// ---------------------------------------------------------------------------
__global__ __launch_bounds__(256) void prep_kernel(
    const float* __restrict__ W, const float* __restrict__ words,
    float* __restrict__ WT, float* __restrict__ wordsT) {
  const int tid = threadIdx.x;
  const int tx = tid & 31, ty = tid >> 5;
  if (blockIdx.x < 192) {
    // W: 32x32 tile transpose; tiles: 8 (c) x 24 (e)
    __shared__ float t[32][33];
    const int tc = blockIdx.x / 24, te = blockIdx.x % 24;
    const int c0 = tc * 32, e0 = te * 32;
#pragma unroll
    for (int k = 0; k < 4; ++k) {
      const int r = ty + 8 * k;
      t[r][tx] = W[(c0 + r) * E_ + e0 + tx];  // coalesced over tx
    }
    __syncthreads();
#pragma unroll
    for (int k = 0; k < 4; ++k) {
      const int r = ty + 8 * k;
      WT[(e0 + r) * NC_ + c0 + tx] = t[tx][r];  // coalesced over tx
    }
  } else {
    // words[b]: 32(m) x 768(e) -> wordsT[b]: 768(e) x 32(m). tiles: 32 b x 24 e
    __shared__ float t[32][33];
    const int idx = blockIdx.x - 192;
    const int b = idx / 24, te = idx % 24;
    const int e0 = te * 32;
    const float* wsrc = words + (size_t)b * MW_ * E_;
    float* wdst = wordsT + (size_t)b * E_ * MW_;
#pragma unroll
    for (int k = 0; k < 4; ++k) {
      const int m = ty + 8 * k;
      t[m][tx] = wsrc[m * E_ + e0 + tx];        // coalesced over tx (e)
    }
    __syncthreads();
#pragma unroll
    for (int k = 0; k < 4; ++k) {
      const int e = ty + 8 * k;
      wdst[(e0 + e) * MW_ + tx] = t[tx][e];     // coalesced over tx (m)
    }
  }
}

// ---------------------------------------------------------------------------
// Stage 1a: words_p partials. Block = (batch, e-chunk of 96). lane = c.
// part layout: [chunk][b][m][c].
// ---------------------------------------------------------------------------
__global__ __launch_bounds__(256) void stage1_partial(
    const float* __restrict__ wordsT, const float* __restrict__ WT,
    float* __restrict__ part) {
  const int c = threadIdx.x;
  const int b = blockIdx.x >> 3;
  const int chunk = blockIdx.x & 7;
  const int e0 = chunk * 96;
  const float* wt = wordsT + (size_t)b * E_ * MW_;
  float acc[32];
#pragma unroll
  for (int m = 0; m < 32; ++m) acc[m] = 0.f;
#pragma unroll 2
  for (int e = e0; e < e0 + 96; ++e) {
    const float wv = WT[(size_t)e * NC_ + c];   // coalesced over lanes
    const float* wr = wt + e * MW_;             // uniform, contiguous
#pragma unroll
    for (int m = 0; m < 32; ++m) acc[m] = fmaf(wv, wr[m], acc[m]);
  }
  float* pp = part + ((size_t)chunk * 32 + b) * 32 * 256;
#pragma unroll
  for (int m = 0; m < 32; ++m) pp[m * 256 + c] = acc[m];  // coalesced
}

// ---------------------------------------------------------------------------
// Stage 2 (R8): 4 px/thread (vf4) + fused conflict-free staging-reduce.
// History:
//   R0 (128us): wp via s_load -> scalar-stream stall, 21% duty/wave.
//   R4 (102us): wp in LDS, 1px, 8 w/CU: 47% VALU.
//   R6 (94us):  2px, 4 w/CU: 50% VALU. R4~R6 flat => per-wave duty ~50%,
//       limited by LDS-byte-per-FMA + dependency bubbles; extra same-SIMD
//       waves (R4) don't fill them.
//   R7 (144us, REGRESSION): manual wa/wb ping-pong (+64 VGPR, broke the
//       compiler's schedule; VALU-cycles +21%) + 32-way-conflict staging
//       writes (917K conflict cyc). Both reverted. KEEPER from R7: 3-kernel
//       structure (-1 launch = ~-40us of total).
// R8:
//   - 4 px/thread via vf4: 128 FMA-insts per 8 ds_read_b128 per channel
//     (2x R6 ratio). 256 blocks x 128 thr = 2 waves/CU on 2 SIMDs.
//   - launch_bounds(128,1): VGPR cap 512; waves sit on different SIMDs, so
//     even 300+ VGPR costs nothing. NO allocator squeeze possible.
//   - staging-reduce: thread owns vf4 chunks (c=v>>3, mq=v&7): LDS writes
//     are lane-consecutive vf4 (conflict-free); part reads pack 8 lanes per
//     32B segment (L2-resident).
//   - inner loops: direct LDS operands, compiler-scheduled (R7 lesson).
// ---------------------------------------------------------------------------
__global__ __launch_bounds__(128, 1) void attention_fused(
    const float* __restrict__ images, const float* __restrict__ part,
    const float* __restrict__ bias, const void* __restrict__ mask_raw,
    float* __restrict__ out_w, float* __restrict__ out_a) {
  __shared__ float lwp[NC_ * MW_];  // [c][m], 32 KB
  __shared__ int is_word;
  const int tid = threadIdx.x;            // 0..127
  const int b = blockIdx.x & 31;          // batch
  const int po = ((blockIdx.x >> 5) << 7) + tid;  // vf4 col in [0,1024)
  const vf4* imgb = (const vf4*)(images + (size_t)b * NC_ * HW_);

  if (tid == 0) is_word = 1;

  // Image prefetch FIRST -- flies during staging below.
  vf4 cur[8];
#pragma unroll
  for (int j = 0; j < 8; ++j)
    cur[j] = __builtin_nontemporal_load(&imgb[((size_t)j << 10) + po]);

  // Fused staging-reduce: lwp[c][m] = bias[c] + sum_k part[k][b][m][c].
  // Thread owns vf4 chunks v = tid + 128*k2: (c = v>>3, mq = v&7) ->
  // writes dst[v] lane-consecutive (conflict-free); reads: 8 lanes share
  // each 32B segment of part (coalesced, L2-resident).
  {
    vf4* dst = (vf4*)lwp;
#pragma unroll
    for (int k2 = 0; k2 < 16; ++k2) {
      const int v = tid + (k2 << 7);
      const int c = v >> 3;
      const int mq = v & 7;
      const float bc = bias[c];
      float v0 = bc, v1 = bc, v2 = bc, v3 = bc;
#pragma unroll
      for (int pk = 0; pk < 8; ++pk) {
        const float* pp = part + (((size_t)pk * 32 + b) * 32) * 256;
        const int mb = mq << 2;
        v0 += pp[(mb + 0) * 256 + c];
        v1 += pp[(mb + 1) * 256 + c];
        v2 += pp[(mb + 2) * 256 + c];
        v3 += pp[(mb + 3) * 256 + c];
      }
      vf4 t; t.x = v0; t.y = v1; t.z = v2; t.w = v3;
      dst[v] = t;
    }
  }
  __syncthreads();  // lwp ready; is_word init visible

  // Mask layout detection (reads only first 1024 bytes: safe for any layout).
  {
    const int* mi = (const int*)mask_raw;
#pragma unroll
    for (int q = 0; q < 2; ++q) {
      const int v = mi[q * 128 + tid];
      if (v != 0 && v != 1 && v != 0x3F800000) is_word = 0;
    }
  }
  __syncthreads();
  unsigned mbits = 0;
  if (is_word) {
    const int* mi = (const int*)mask_raw;
#pragma unroll
    for (int m = 0; m < 32; ++m)
      mbits |= (mi[(b << 5) + m] != 0 ? 1u : 0u) << m;
  } else {
    const unsigned char* mb = (const unsigned char*)mask_raw;
#pragma unroll
    for (int m = 0; m < 32; ++m)
      mbits |= (mb[(b << 5) + m] != 0 ? 1u : 0u) << m;
  }

  // ---- score loop: s{0..3}[m] = sum_c img[c][p..] * wp[c][m] ----
  float s0[32], s1[32], s2[32], s3[32];
#pragma unroll
  for (int m = 0; m < 32; ++m) { s0[m] = 0.f; s1[m] = 0.f; s2[m] = 0.f; s3[m] = 0.f; }

#pragma unroll 1
  for (int c0 = 0; c0 < 256; c0 += 8) {
    vf4 nxt[8];
    if (c0 + 8 < 256) {
#pragma unroll
      for (int j = 0; j < 8; ++j)
        nxt[j] = __builtin_nontemporal_load(&imgb[((size_t)(c0 + 8 + j) << 10) + po]);
    }
#pragma unroll
    for (int j = 0; j < 8; ++j) {
      const float* wr = lwp + ((c0 + j) << 5);  // broadcast LDS row
      const vf4 v = cur[j];
#pragma unroll
      for (int m = 0; m < 32; ++m) {
        s0[m] = fmaf(v.x, wr[m], s0[m]);
        s1[m] = fmaf(v.y, wr[m], s1[m]);
        s2[m] = fmaf(v.z, wr[m], s2[m]);
        s3[m] = fmaf(v.w, wr[m], s3[m]);
      }
    }
#pragma unroll
    for (int j = 0; j < 8; ++j) cur[j] = nxt[j];  // dead on last iter
  }

  // ---- softmax over m for the 4 pixels (scale 1/sqrt(256) = 0.0625) ----
  float mx0 = NEG_BIG, mx1 = NEG_BIG, mx2 = NEG_BIG, mx3 = NEG_BIG;
#pragma unroll
  for (int m = 0; m < 32; ++m) {
    s0[m] *= 0.0625f; s1[m] *= 0.0625f; s2[m] *= 0.0625f; s3[m] *= 0.0625f;
    if (!((mbits >> m) & 1u)) {
      mx0 = fmaxf(mx0, s0[m]); mx1 = fmaxf(mx1, s1[m]);
      mx2 = fmaxf(mx2, s2[m]); mx3 = fmaxf(mx3, s3[m]);
    }
  }
  float sum0 = 0.f, sum1 = 0.f, sum2 = 0.f, sum3 = 0.f;
#pragma unroll
  for (int m = 0; m < 32; ++m) {
    const bool msk = (mbits >> m) & 1u;
    const float e0 = msk ? 0.f : __expf(s0[m] - mx0);
    const float e1 = msk ? 0.f : __expf(s1[m] - mx1);
    const float e2 = msk ? 0.f : __expf(s2[m] - mx2);
    const float e3 = msk ? 0.f : __expf(s3[m] - mx3);
    s0[m] = e0; s1[m] = e1; s2[m] = e2; s3[m] = e3;
    sum0 += e0; sum1 += e1; sum2 += e2; sum3 += e3;
  }
  const float inv0 = 1.f / sum0, inv1 = 1.f / sum1;
  const float inv2 = 1.f / sum2, inv3 = 1.f / sum3;
  vf4* oa = (vf4*)out_a;
#pragma unroll
  for (int m = 0; m < 32; ++m) {
    s0[m] *= inv0; s1[m] *= inv1; s2[m] *= inv2; s3[m] *= inv3;
    vf4 a; a.x = s0[m]; a.y = s1[m]; a.z = s2[m]; a.w = s3[m];
    __builtin_nontemporal_store(a, &oa[((size_t)((b << 5) + m) << 10) + po]);
  }

  // ---- PV loop: out[c][p..] = sum_m wp[c][m] * a[m] ----
  vf4* ow = (vf4*)out_w;
#pragma unroll 1
  for (int c0 = 0; c0 < 256; c0 += 8) {
#pragma unroll
    for (int j = 0; j < 8; ++j) {
      const int c = c0 + j;
      const float* wr = lwp + (c << 5);
      float o0 = 0.f, o1 = 0.f, o2 = 0.f, o3 = 0.f;
#pragma unroll
      for (int m = 0; m < 32; ++m) {
        o0 = fmaf(wr[m], s0[m], o0);
        o1 = fmaf(wr[m], s1[m], o1);
        o2 = fmaf(wr[m], s2[m], o2);
        o3 = fmaf(wr[m], s3[m], o3);
      }
      vf4 o; o.x = o0; o.y = o1; o.z = o2; o.w = o3;
      __builtin_nontemporal_store(o, &ow[((size_t)((b << 8) + c) << 10) + po]);
    }
  }
}

// ---------------------------------------------------------------------------
extern "C" void kernel_launch(void* const* d_in, const int* in_sizes, int n_in,
                              void* d_out, int out_size, void* d_ws, size_t ws_size,
                              hipStream_t stream) {
  const float* images = (const float*)d_in[0];
  const float* words  = (const float*)d_in[1];
  const void*  mask   = d_in[2];
  const float* W      = (const float*)d_in[3];
  const float* bias   = (const float*)d_in[4];

  float* ws     = (float*)d_ws;
  float* part   = ws + PART_OFF;
  float* WT     = ws + WT_OFF;
  float* wordsT = ws + WORDST_OFF;

  float* out_w = (float*)d_out;
  float* out_a = out_w + (size_t)B_ * NC_ * HW_;

  prep_kernel<<<960, 256, 0, stream>>>(W, words, WT, wordsT);
  stage1_partial<<<256, 256, 0, stream>>>(wordsT, WT, part);
  attention_fused<<<256, 128, 0, stream>>>(images, part, bias, mask, out_w, out_a);
}

// Round 10
// 310.510 us; speedup vs baseline: 1.1665x; 1.1665x over previous
//
#include <hip/hip_runtime.h>
#include <math.h>

// Problem shape (fixed by reference setup_inputs):
//   images [32][256][64][64] fp32, words [32][32][768] fp32, mask [32][32] bool,
//   W [256][768] fp32, b [256] fp32
//   out0 weighted_words [32][256][64][64], out1 attn_out [32][32][64][64], fp32 concat.
#define B_   32
#define NC_  256
#define HW_  4096
#define MW_  32
#define E_   768
#define NEG_BIG -3.0e38f

// Native Clang vector types: __builtin_nontemporal_* accepts these
// (HIP's float2/float4 are classes and are rejected -- R5 compile failure).
typedef float vf2 __attribute__((ext_vector_type(2)));
typedef float vf4 __attribute__((ext_vector_type(4)));

// Workspace layout (float offsets).
#define PART_OFF   0          // partial GEMM: 8 chunks * 32b * 32m * 256c = 2097152 floats
#define WT_OFF     2359296    // W transposed [e][c]: 196608 floats
#define WORDST_OFF 2555904    // words transposed [b][e][m]: 786432 floats

// ---------------------------------------------------------------------------
// Prep: tiled transposes only (W 256x768 -> WT 768x256; words[b] 32x768 ->
// wordsT[b] 768x32). Mask handling lives in attention.
// Blocks 0..191: W transpose. 192..959: words transpose.
// ---------------------------------------------------------------------------
__global__ __launch_bounds__(256) void prep_kernel(
    const float* __restrict__ W, const float* __restrict__ words,
    float* __restrict__ WT, float* __restrict__ wordsT) {
  const int tid = threadIdx.x;
  const int tx = tid & 31, ty = tid >> 5;
  if (blockIdx.x < 192) {
    // W: 32x32 tile transpose; tiles: 8 (c) x 24 (e)
    __shared__ float t[32][33];
    const int tc = blockIdx.x / 24, te = blockIdx.x % 24;
    const int c0 = tc * 32, e0 = te * 32;
#pragma unroll
    for (int k = 0; k < 4; ++k) {
      const int r = ty + 8 * k;
      t[r][tx] = W[(c0 + r) * E_ + e0 + tx];  // coalesced over tx
    }
    __syncthreads();
#pragma unroll
    for (int k = 0; k < 4; ++k) {
      const int r = ty + 8 * k;
      WT[(e0 + r) * NC_ + c0 + tx] = t[tx][r];  // coalesced over tx
    }
  } else {
    // words[b]: 32(m) x 768(e) -> wordsT[b]: 768(e) x 32(m). tiles: 32 b x 24 e
    __shared__ float t[32][33];
    const int idx = blockIdx.x - 192;
    const int b = idx / 24, te = idx % 24;
    const int e0 = te * 32;
    const float* wsrc = words + (size_t)b * MW_ * E_;
    float* wdst = wordsT + (size_t)b * E_ * MW_;
#pragma unroll
    for (int k = 0; k < 4; ++k) {
      const int m = ty + 8 * k;
      t[m][tx] = wsrc[m * E_ + e0 + tx];        // coalesced over tx (e)
    }
    __syncthreads();
#pragma unroll
    for (int k = 0; k < 4; ++k) {
      const int e = ty + 8 * k;
      wdst[(e0 + e) * MW_ + tx] = t[tx][e];     // coalesced over tx (m)
    }
  }
}

// ---------------------------------------------------------------------------
// Stage 1a: words_p partials. Block = (batch, e-chunk of 96). lane = c.
// part layout: [chunk][b][m][c].
// ---------------------------------------------------------------------------
__global__ __launch_bounds__(256) void stage1_partial(
    const float* __restrict__ wordsT, const float* __restrict__ WT,
    float* __restrict__ part) {
  const int c = threadIdx.x;
  const int b = blockIdx.x >> 3;
  const int chunk = blockIdx.x & 7;
  const int e0 = chunk * 96;
  const float* wt = wordsT + (size_t)b * E_ * MW_;
  float acc[32];
#pragma unroll
  for (int m = 0; m < 32; ++m) acc[m] = 0.f;
#pragma unroll 2
  for (int e = e0; e < e0 + 96; ++e) {
    const float wv = WT[(size_t)e * NC_ + c];   // coalesced over lanes
    const float* wr = wt + e * MW_;             // uniform, contiguous
#pragma unroll
    for (int m = 0; m < 32; ++m) acc[m] = fmaf(wv, wr[m], acc[m]);
  }
  float* pp = part + ((size_t)chunk * 32 + b) * 32 * 256;
#pragma unroll
  for (int m = 0; m < 32; ++m) pp[m * 256 + c] = acc[m];  // coalesced
}

// ---------------------------------------------------------------------------
// Stage 2 (R10): R9 structure with the exchange bug fixed.
// History:
//   R0 (128us): wp via s_load: scalar stall, 21% duty.
//   R4 (102us): wp in LDS, 1px, 2 waves/SIMD: 47% VALU.
//   R6 (94us):  2px, 1 wave/SIMD: 50% VALU.
//   R7 (144us): manual ping-pong broke compiler schedule. Reverted.
//   R8 (153us): 4px/thread but only 512 waves = 2/4 SIMDs active;
//       per-active-SIMD duty ~58% (best yet) -- grid error, not structure.
//   R9 (WRONG): 4px + c-split-2 across wave pairs; all-reduce exchanged
//       only quads 0..3 (m 0..15) of each 8-quad score vector -- m 16..31
//       stayed partial -> absmax 2.29. Structure never evaluated.
// R10 = R9 with a correct exchange: 4 rounds (one per px), each moving all
//   8 quads of s_i through xbuf[2][8][128] (lane-consecutive vf4,
//   conflict-free), 7 barriers total. Everything else unchanged:
//   block = 256 thr = 4 waves = 2 px-groups x 2 c-halves; grid = 256
//   blocks = 1024 waves = 1 wave/SIMD on ALL SIMDs; per wave 128 channels
//   x 4 px = 128 FMA-insts per 8 ds_read_b128; launch_bounds(256,1) ->
//   VGPR cap 512, no allocator squeeze.
// ---------------------------------------------------------------------------
__global__ __launch_bounds__(256, 1) void attention_fused(
    const float* __restrict__ images, const float* __restrict__ part,
    const float* __restrict__ bias, const void* __restrict__ mask_raw,
    float* __restrict__ out_w, float* __restrict__ out_a) {
  __shared__ float lwp[NC_ * MW_];   // [c][m], 32 KB
  __shared__ vf4 xbuf[2][8][128];    // exchange: [h][quad][q], 32 KB
  __shared__ int is_word;
  const int tid = threadIdx.x;            // 0..255
  const int lane = tid & 63;
  const int w = tid >> 6;                 // wave 0..3
  const int h = w & 1;                    // c-half of this wave
  const int q = lane + ((w >> 1) << 6);   // px-thread 0..127
  const int b = blockIdx.x & 31;          // batch (batch-minor grid)
  const int po = ((blockIdx.x >> 5) << 7) + q;  // vf4 col in [0,1024)
  // image base for this wave's channel half, pre-offset by po
  const vf4* imgh = (const vf4*)(images + (size_t)b * NC_ * HW_)
                    + (((size_t)(h << 7)) << 10) + po;

  if (tid == 0) is_word = 1;

  // Image prefetch FIRST -- flies during staging below.
  vf4 cur[8];
#pragma unroll
  for (int j = 0; j < 8; ++j)
    cur[j] = __builtin_nontemporal_load(&imgh[(size_t)j << 10]);

  // Fused staging-reduce: lwp[c][m] = bias[c] + sum_k part[k][b][m][c].
  // Thread owns vf4 chunks v: (c = v>>3, mq = v&7) -> lane-consecutive
  // writes (conflict-free, R8-verified); coalesced part reads.
  {
    vf4* dst = (vf4*)lwp;
#pragma unroll
    for (int k2 = 0; k2 < 8; ++k2) {
      const int v = tid + (k2 << 8);
      const int c = v >> 3;
      const int mq = v & 7;
      const float bc = bias[c];
      float v0 = bc, v1 = bc, v2 = bc, v3 = bc;
#pragma unroll
      for (int pk = 0; pk < 8; ++pk) {
        const float* pp = part + (((size_t)pk * 32 + b) * 32) * 256;
        const int mb = mq << 2;
        v0 += pp[(mb + 0) * 256 + c];
        v1 += pp[(mb + 1) * 256 + c];
        v2 += pp[(mb + 2) * 256 + c];
        v3 += pp[(mb + 3) * 256 + c];
      }
      vf4 t; t.x = v0; t.y = v1; t.z = v2; t.w = v3;
      dst[v] = t;
    }
  }

  // Mask layout detection (first 1024 bytes only: safe for any layout).
  {
    const int* mi = (const int*)mask_raw;
    const int vv = mi[tid];
    if (vv != 0 && vv != 1 && vv != 0x3F800000) is_word = 0;
  }
  __syncthreads();  // lwp ready; is_word final
  unsigned mbits = 0;
  if (is_word) {
    const int* mi = (const int*)mask_raw;
#pragma unroll
    for (int m = 0; m < 32; ++m)
      mbits |= (mi[(b << 5) + m] != 0 ? 1u : 0u) << m;
  } else {
    const unsigned char* mb = (const unsigned char*)mask_raw;
#pragma unroll
    for (int m = 0; m < 32; ++m)
      mbits |= (mb[(b << 5) + m] != 0 ? 1u : 0u) << m;
  }

  // ---- score loop: this wave's 128 channels, 4 px ----
  float s0[32], s1[32], s2[32], s3[32];
#pragma unroll
  for (int m = 0; m < 32; ++m) { s0[m] = 0.f; s1[m] = 0.f; s2[m] = 0.f; s3[m] = 0.f; }

#pragma unroll 1
  for (int c0 = 0; c0 < 128; c0 += 8) {
    vf4 nxt[8];
    if (c0 + 8 < 128) {
#pragma unroll
      for (int j = 0; j < 8; ++j)
        nxt[j] = __builtin_nontemporal_load(&imgh[(size_t)(c0 + 8 + j) << 10]);
    }
#pragma unroll
    for (int j = 0; j < 8; ++j) {
      const float* wr = lwp + (((h << 7) + c0 + j) << 5);  // broadcast row
      const vf4 v = cur[j];
#pragma unroll
      for (int m = 0; m < 32; ++m) {
        s0[m] = fmaf(v.x, wr[m], s0[m]);
        s1[m] = fmaf(v.y, wr[m], s1[m]);
        s2[m] = fmaf(v.z, wr[m], s2[m]);
        s3[m] = fmaf(v.w, wr[m], s3[m]);
      }
    }
#pragma unroll
    for (int j = 0; j < 8; ++j) cur[j] = nxt[j];  // dead on last iter
  }

  // ---- all-reduce partial scores between wave pairs (h <-> h^1) ----
  // R9 BUG FIX: each s_i is 8 quads (m 0..31); exchange ALL 8 per round.
  // 4 rounds, one per pixel; xbuf writes/reads lane-consecutive vf4.
  const int ho = h ^ 1;
#define XCHG(SV)                                                        \
  {                                                                     \
    _Pragma("unroll")                                                   \
    for (int vq = 0; vq < 8; ++vq) {                                    \
      vf4 t;                                                            \
      t.x = SV[4*vq]; t.y = SV[4*vq+1]; t.z = SV[4*vq+2]; t.w = SV[4*vq+3]; \
      xbuf[h][vq][q] = t;                                               \
    }                                                                   \
    __syncthreads();                                                    \
    _Pragma("unroll")                                                   \
    for (int vq = 0; vq < 8; ++vq) {                                    \
      const vf4 t = xbuf[ho][vq][q];                                    \
      SV[4*vq] += t.x; SV[4*vq+1] += t.y;                               \
      SV[4*vq+2] += t.z; SV[4*vq+3] += t.w;                             \
    }                                                                   \
  }
  XCHG(s0);
  __syncthreads();
  XCHG(s1);
  __syncthreads();
  XCHG(s2);
  __syncthreads();
  XCHG(s3);
#undef XCHG

  // ---- softmax over m, 4 px (scale 1/sqrt(256) = 0.0625) ----
  // Both waves of a pair hold identical sums -> redundant (uniform) softmax.
  float mx0 = NEG_BIG, mx1 = NEG_BIG, mx2 = NEG_BIG, mx3 = NEG_BIG;
#pragma unroll
  for (int m = 0; m < 32; ++m) {
    s0[m] *= 0.0625f; s1[m] *= 0.0625f; s2[m] *= 0.0625f; s3[m] *= 0.0625f;
    if (!((mbits >> m) & 1u)) {
      mx0 = fmaxf(mx0, s0[m]); mx1 = fmaxf(mx1, s1[m]);
      mx2 = fmaxf(mx2, s2[m]); mx3 = fmaxf(mx3, s3[m]);
    }
  }
  float sum0 = 0.f, sum1 = 0.f, sum2 = 0.f, sum3 = 0.f;
#pragma unroll
  for (int m = 0; m < 32; ++m) {
    const bool msk = (mbits >> m) & 1u;
    const float e0 = msk ? 0.f : __expf(s0[m] - mx0);
    const float e1 = msk ? 0.f : __expf(s1[m] - mx1);
    const float e2 = msk ? 0.f : __expf(s2[m] - mx2);
    const float e3 = msk ? 0.f : __expf(s3[m] - mx3);
    s0[m] = e0; s1[m] = e1; s2[m] = e2; s3[m] = e3;
    sum0 += e0; sum1 += e1; sum2 += e2; sum3 += e3;
  }
  const float inv0 = 1.f / sum0, inv1 = 1.f / sum1;
  const float inv2 = 1.f / sum2, inv3 = 1.f / sum3;
#pragma unroll
  for (int m = 0; m < 32; ++m) {
    s0[m] *= inv0; s1[m] *= inv1; s2[m] *= inv2; s3[m] *= inv3;
  }
  if (h == 0) {
    vf4* oa = (vf4*)out_a;
#pragma unroll
    for (int m = 0; m < 32; ++m) {
      vf4 a; a.x = s0[m]; a.y = s1[m]; a.z = s2[m]; a.w = s3[m];
      __builtin_nontemporal_store(a, &oa[(((size_t)(b << 5) + m) << 10) + po]);
    }
  }

  // ---- PV loop: this wave's 128 channels, 4 px ----
  vf4* ow = (vf4*)out_w;
#pragma unroll 1
  for (int c0 = 0; c0 < 128; c0 += 8) {
#pragma unroll
    for (int j = 0; j < 8; ++j) {
      const int c = (h << 7) + c0 + j;
      const float* wr = lwp + (c << 5);
      float o0 = 0.f, o1 = 0.f, o2 = 0.f, o3 = 0.f;
#pragma unroll
      for (int m = 0; m < 32; ++m) {
        o0 = fmaf(wr[m], s0[m], o0);
        o1 = fmaf(wr[m], s1[m], o1);
        o2 = fmaf(wr[m], s2[m], o2);
        o3 = fmaf(wr[m], s3[m], o3);
      }
      vf4 o; o.x = o0; o.y = o1; o.z = o2; o.w = o3;
      __builtin_nontemporal_store(o, &ow[(((size_t)(b << 8) + c) << 10) + po]);
    }
  }
}

// ---------------------------------------------------------------------------
extern "C" void kernel_launch(void* const* d_in, const int* in_sizes, int n_in,
                              void* d_out, int out_size, void* d_ws, size_t ws_size,
                              hipStream_t stream) {
  const float* images = (const float*)d_in[0];
  const float* words  = (const float*)d_in[1];
  const void*  mask   = d_in[2];
  const float* W      = (const float*)d_in[3];
  const float* bias   = (const float*)d_in[4];

  float* ws     = (float*)d_ws;
  float* part   = ws + PART_OFF;
  float* WT     = ws + WT_OFF;
  float* wordsT = ws + WORDST_OFF;

  float* out_w = (float*)d_out;
  float* out_a = out_w + (size_t)B_ * NC_ * HW_;

  prep_kernel<<<960, 256, 0, stream>>>(W, words, WT, wordsT);
  stage1_partial<<<256, 256, 0, stream>>>(wordsT, WT, part);
  attention_fused<<<256, 256, 0, stream>>>(images, part, bias, mask, out_w, out_a);
}